// Round 6
// baseline (205.636 us; speedup 1.0000x reference)
//
#include <hip/hip_runtime.h>
#include <math.h>

// iSQRT-COV: B=64, C=128, n=3136.
// 1) gram: Gpart[ks] = X-chunk @ X-chunk^T via split-bf16 MFMA (896 blocks)
// 2) reduce: sigma = sum(Gpart)/n - mu mu^T -> split-bf16 planes + tr partials
// 3) ns: fused Newton-Schulz, 64 blocks x 512 threads (8 waves, 2/SIMD);
//    P1 on all waves, P2 (Y-update, waves 0-3) || P3 (Z-update, waves 4-7).

#define CC 128
#define NN 3136
#define BB 64
#define KS 14
#define KCHUNK 224            // NN/KS = 7 ksteps of 32
#define MATS (CC * CC)
#define OUTLEN 8256
#define PSTR 136              // ns plane row stride in bf16
#define SSTR 34               // gram stage row stride in bf16 (odd dwords)

typedef float f32x4 __attribute__((ext_vector_type(4)));
typedef short s16x8 __attribute__((ext_vector_type(8)));
typedef short s16x4 __attribute__((ext_vector_type(4)));
typedef __bf16 bf16x8 __attribute__((ext_vector_type(8)));

__device__ __forceinline__ unsigned short f2b(float f) {
    unsigned u = __builtin_bit_cast(unsigned, f);
    unsigned r = u + 0x7fffu + ((u >> 16) & 1u);
    return (unsigned short)(r >> 16);
}
__device__ __forceinline__ float b2f(unsigned short s) {
    return __builtin_bit_cast(float, ((unsigned)s) << 16);
}

__device__ __forceinline__ f32x4 MF(s16x8 a, s16x8 b, f32x4 c) {
    return __builtin_amdgcn_mfma_f32_16x16x32_bf16(
        __builtin_bit_cast(bf16x8, a), __builtin_bit_cast(bf16x8, b), c, 0, 0, 0);
}

// ---------------------------------------------------------------------------
// Gram partial via split-bf16 MFMA. grid (BB, KS), block 256 (4 waves).
// ---------------------------------------------------------------------------
__global__ __launch_bounds__(256, 1)
void gram_kernel(const float* __restrict__ x, float* __restrict__ Gpart,
                 float* __restrict__ rspart)
{
    __shared__ short Xs[2][2][128 * SSTR];   // [buf][hi/lo][row*SSTR+k]
    const int b = blockIdx.x, ks = blockIdx.y;
    const int tid  = threadIdx.x;
    const int wave = tid >> 6, lane = tid & 63;
    const int q = lane >> 4, l15 = lane & 15;
    const int i0 = (wave >> 1) * 64, j0 = (wave & 1) * 64;

    const float* __restrict__ Xb = x + (size_t)b * CC * NN + (size_t)ks * KCHUNK;
    const int lrow = tid >> 3;        // 0..31
    const int lf   = tid & 7;         // 0..7

    f32x4 acc[4][4];
#pragma unroll
    for (int rt = 0; rt < 4; ++rt)
#pragma unroll
        for (int ct = 0; ct < 4; ++ct) acc[rt][ct] = (f32x4){0.f, 0.f, 0.f, 0.f};
    float rs[4] = {0.f, 0.f, 0.f, 0.f};

    float4 ld[4];
#pragma unroll
    for (int p = 0; p < 4; ++p)
        ld[p] = *(const float4*)(Xb + (size_t)(lrow + 32 * p) * NN + lf * 4);

#pragma unroll
    for (int p = 0; p < 4; ++p) {
        const float4 v = ld[p];
        rs[p] += v.x + v.y + v.z + v.w;
        float f[4] = {v.x, v.y, v.z, v.w};
        s16x4 h, l;
#pragma unroll
        for (int r = 0; r < 4; ++r) {
            unsigned short hh = f2b(f[r]);
            h[r] = (short)hh;
            l[r] = (short)f2b(f[r] - b2f(hh));
        }
        const int off = (lrow + 32 * p) * SSTR + lf * 4;
        *(s16x4*)(&Xs[0][0][off]) = h;
        *(s16x4*)(&Xs[0][1][off]) = l;
    }
    __syncthreads();

    for (int kt = 0; kt < 7; ++kt) {
        const int cur = kt & 1;
        if (kt < 6) {
#pragma unroll
            for (int p = 0; p < 4; ++p)
                ld[p] = *(const float4*)(Xb + (size_t)(lrow + 32 * p) * NN + (kt + 1) * 32 + lf * 4);
        }
        s16x8 ah[4], al[4], bh[4], bl[4];
#pragma unroll
        for (int t = 0; t < 4; ++t) {
            ah[t] = *(const s16x8*)(&Xs[cur][0][(i0 + t * 16 + l15) * SSTR + q * 8]);
            al[t] = *(const s16x8*)(&Xs[cur][1][(i0 + t * 16 + l15) * SSTR + q * 8]);
            bh[t] = *(const s16x8*)(&Xs[cur][0][(j0 + t * 16 + l15) * SSTR + q * 8]);
            bl[t] = *(const s16x8*)(&Xs[cur][1][(j0 + t * 16 + l15) * SSTR + q * 8]);
        }
#pragma unroll
        for (int rt = 0; rt < 4; ++rt)
#pragma unroll
            for (int ct = 0; ct < 4; ++ct) {
                acc[rt][ct] = MF(ah[rt], bh[ct], acc[rt][ct]);
                acc[rt][ct] = MF(ah[rt], bl[ct], acc[rt][ct]);
                acc[rt][ct] = MF(al[rt], bh[ct], acc[rt][ct]);
            }
        if (kt < 6) {
#pragma unroll
            for (int p = 0; p < 4; ++p) {
                const float4 v = ld[p];
                rs[p] += v.x + v.y + v.z + v.w;
                float f[4] = {v.x, v.y, v.z, v.w};
                s16x4 h, l;
#pragma unroll
                for (int r = 0; r < 4; ++r) {
                    unsigned short hh = f2b(f[r]);
                    h[r] = (short)hh;
                    l[r] = (short)f2b(f[r] - b2f(hh));
                }
                const int off = (lrow + 32 * p) * SSTR + lf * 4;
                *(s16x4*)(&Xs[cur ^ 1][0][off]) = h;
                *(s16x4*)(&Xs[cur ^ 1][1][off]) = l;
            }
            __syncthreads();
        }
    }

    float* __restrict__ Gb = Gpart + (size_t)(ks * BB + b) * MATS;
#pragma unroll
    for (int rt = 0; rt < 4; ++rt)
#pragma unroll
        for (int ct = 0; ct < 4; ++ct)
#pragma unroll
            for (int r = 0; r < 4; ++r) {
                const int m = i0 + rt * 16 + q * 4 + r;
                const int n = j0 + ct * 16 + l15;
                Gb[m * CC + n] = acc[rt][ct][r];
            }
#pragma unroll
    for (int p = 0; p < 4; ++p) {
        float v = rs[p];
        v += __shfl_xor(v, 1);
        v += __shfl_xor(v, 2);
        v += __shfl_xor(v, 4);
        if ((lane & 7) == 0)
            rspart[(size_t)(ks * BB + b) * CC + lrow + 32 * p] = v;
    }
}

// ---------------------------------------------------------------------------
// Reduce: sigma = sum_ks(Gpart)/n - mu mu^T -> split-bf16 planes + tr partials.
// grid (BB, 4), block 256.
// ---------------------------------------------------------------------------
__global__ __launch_bounds__(256, 2)
void reduce_kernel(const float* __restrict__ Gpart, const float* __restrict__ rspart,
                   short* __restrict__ Shi, short* __restrict__ Slo,
                   float* __restrict__ trpart)
{
    __shared__ float mu[CC];
    __shared__ float red[256];
    const int b = blockIdx.x, qr = blockIdx.y;
    const int tid = threadIdx.x;

    if (tid < CC) {
        float s = 0.f;
#pragma unroll
        for (int ks = 0; ks < KS; ++ks)
            s += rspart[(size_t)(ks * BB + b) * CC + tid];
        mu[tid] = s * (1.0f / NN);
    }
    __syncthreads();

    const float4* __restrict__ GP4 = (const float4*)Gpart;
    float trsum = 0.f;
#pragma unroll
    for (int j = 0; j < 4; ++j) {
        const int idx4 = qr * 1024 + tid + 256 * j;
        float4 tb[KS];
#pragma unroll
        for (int ks = 0; ks < KS; ++ks)
            tb[ks] = GP4[(size_t)(ks * BB + b) * 4096 + idx4];
        const int row = idx4 >> 5;
        const int c4  = (idx4 & 31) << 2;
        float g[4] = {0.f, 0.f, 0.f, 0.f};
#pragma unroll
        for (int ks = 0; ks < KS; ++ks) {
            g[0] += tb[ks].x; g[1] += tb[ks].y;
            g[2] += tb[ks].z; g[3] += tb[ks].w;
        }
        const float mr = mu[row];
        s16x4 h, l;
#pragma unroll
        for (int r = 0; r < 4; ++r) {
            const float s = g[r] * (1.0f / NN) - mr * mu[c4 + r];
            unsigned short hh = f2b(s);
            h[r] = (short)hh;
            l[r] = (short)f2b(s - b2f(hh));
            if (row == c4 + r) trsum += s;
        }
        *(s16x4*)(Shi + (size_t)b * MATS + idx4 * 4) = h;
        *(s16x4*)(Slo + (size_t)b * MATS + idx4 * 4) = l;
    }
    red[tid] = trsum;
    __syncthreads();
    for (int s = 128; s > 0; s >>= 1) {
        if (tid < s) red[tid] += red[tid + s];
        __syncthreads();
    }
    if (tid == 0) trpart[b * 4 + qr] = red[0];
}

// ---------------------------------------------------------------------------
// Fused NS: 512 threads (8 waves, 2/SIMD). P1 (D=0.5I-0.5*Z@Y) on all 8 waves
// (32x64 tiles); P2 (Y+=Y@D, waves 0-3) and P3 (Z+=D@Z, waves 4-7) run
// concurrently on 32x128 strips. Y,Z fp32 in regs of their wave group.
// All NS matrices symmetric -> transposed packed LDS writes valid.
// ---------------------------------------------------------------------------
__global__ __launch_bounds__(512, 2)
void ns_kernel(const short* __restrict__ Shi, const short* __restrict__ Slo,
               const float* __restrict__ trpart, float* __restrict__ out)
{
    __shared__ short Yhi[128 * PSTR];
    __shared__ short Ylo[128 * PSTR];
    __shared__ short Dm [128 * PSTR];
    __shared__ short Zm [128 * PSTR];

    const int b = blockIdx.x;
    const int tid  = threadIdx.x;
    const int wave = tid >> 6, lane = tid & 63;
    const int q = lane >> 4, l15 = lane & 15;

    const float tr = trpart[b * 4 + 0] + trpart[b * 4 + 1] +
                     trpart[b * 4 + 2] + trpart[b * 4 + 3];
    const float invtr = 1.0f / tr;
    const float sscale = sqrtf(tr);

    // ---- planes: Y1 = A = sigma/tr (split), D1 = 0.5I-0.5A, Z1 = I+D1 ----
#pragma unroll
    for (int jj = 0; jj < 8; ++jj) {
        const int idx4 = tid + 512 * jj;
        const int row = idx4 >> 5;
        const int c4  = (idx4 & 31) << 2;
        const s16x4 sh = *(const s16x4*)(Shi + (size_t)b * MATS + idx4 * 4);
        const s16x4 sl = *(const s16x4*)(Slo + (size_t)b * MATS + idx4 * 4);
        s16x4 yh, yl, dv, zv;
#pragma unroll
        for (int r = 0; r < 4; ++r) {
            const float a = (b2f((unsigned short)sh[r]) + b2f((unsigned short)sl[r])) * invtr;
            unsigned short hh = f2b(a);
            yh[r] = (short)hh;
            yl[r] = (short)f2b(a - b2f(hh));
            const float dia = (row == c4 + r) ? 0.5f : 0.0f;
            const float d = dia - 0.5f * a;
            dv[r] = (short)f2b(d);
            zv[r] = (short)f2b(((row == c4 + r) ? 1.0f : 0.0f) + d);
        }
        const int off = row * PSTR + c4;
        *(s16x4*)(&Yhi[off]) = yh;
        *(s16x4*)(&Ylo[off]) = yl;
        *(s16x4*)(&Dm[off])  = dv;
        *(s16x4*)(&Zm[off])  = zv;
    }
    __syncthreads();

    const int half = wave >> 2;     // 0: Y-group (P2), 1: Z-group (P3)
    const int w    = wave & 3;
    const int ri0  = w * 32;        // strip row base for P2/P3
    const int p1i  = (wave >> 1) * 32;   // P1 tile coords
    const int p1j  = (wave & 1) * 64;

    // ---- fp32 carry at this wave's strip frag positions ----
    f32x4 c_reg[2][8];
#pragma unroll
    for (int rt = 0; rt < 2; ++rt)
#pragma unroll
        for (int ct = 0; ct < 8; ++ct) {
            const int m0 = ri0 + rt * 16 + q * 4;
            const int n  = ct * 16 + l15;
            const int off = n * PSTR + m0;
            if (half == 0) {
                s16x4 yh = *(s16x4*)(&Yhi[off]);
                s16x4 yl = *(s16x4*)(&Ylo[off]);
#pragma unroll
                for (int r = 0; r < 4; ++r)
                    c_reg[rt][ct][r] = b2f((unsigned short)yh[r]) + b2f((unsigned short)yl[r]);
            } else {
                s16x4 zv = *(s16x4*)(&Zm[off]);
#pragma unroll
                for (int r = 0; r < 4; ++r)
                    c_reg[rt][ct][r] = b2f((unsigned short)zv[r]);
            }
        }

    f32x4 acc8[2][8];

    // ================= it1: P2 only (Y2 = Y1 + Y1@D1; Z1 already = T1) =====
#pragma unroll
    for (int rt = 0; rt < 2; ++rt)
#pragma unroll
        for (int ct = 0; ct < 8; ++ct) acc8[rt][ct] = (f32x4){0.f, 0.f, 0.f, 0.f};
    if (half == 0) {
#pragma unroll
        for (int k0 = 0; k0 < 128; k0 += 32) {
            s16x8 ah[2], al[2], bv[8];
#pragma unroll
            for (int t = 0; t < 2; ++t) {
                ah[t] = *(const s16x8*)(&Yhi[(ri0 + t * 16 + l15) * PSTR + k0 + q * 8]);
                al[t] = *(const s16x8*)(&Ylo[(ri0 + t * 16 + l15) * PSTR + k0 + q * 8]);
            }
#pragma unroll
            for (int ct = 0; ct < 8; ++ct)
                bv[ct] = *(const s16x8*)(&Dm[(ct * 16 + l15) * PSTR + k0 + q * 8]);
#pragma unroll
            for (int rt = 0; rt < 2; ++rt)
#pragma unroll
                for (int ct = 0; ct < 8; ++ct) {
                    acc8[rt][ct] = MF(ah[rt], bv[ct], acc8[rt][ct]);
                    acc8[rt][ct] = MF(al[rt], bv[ct], acc8[rt][ct]);
                }
        }
    }
    __syncthreads();
    if (half == 0) {
#pragma unroll
        for (int rt = 0; rt < 2; ++rt)
#pragma unroll
            for (int ct = 0; ct < 8; ++ct) {
                const int m0 = ri0 + rt * 16 + q * 4;
                const int n  = ct * 16 + l15;
                const int off = n * PSTR + m0;
                s16x4 nh, nl;
#pragma unroll
                for (int r = 0; r < 4; ++r) {
                    const float y = c_reg[rt][ct][r] + acc8[rt][ct][r];
                    c_reg[rt][ct][r] = y;
                    unsigned short hh = f2b(y);
                    nh[r] = (short)hh;
                    nl[r] = (short)f2b(y - b2f(hh));
                }
                *(s16x4*)(&Yhi[off]) = nh;
                *(s16x4*)(&Ylo[off]) = nl;
            }
    }
    __syncthreads();

    // ================= it2..5 =================
    for (int it = 2; it <= 5; ++it) {
        // ---- P1 (all 8 waves): D = 0.5I - 0.5 * Z@Y (Y ~ Yhi) ----
        f32x4 acc4[2][4];
#pragma unroll
        for (int rt = 0; rt < 2; ++rt)
#pragma unroll
            for (int ct = 0; ct < 4; ++ct) acc4[rt][ct] = (f32x4){0.f, 0.f, 0.f, 0.f};
#pragma unroll
        for (int k0 = 0; k0 < 128; k0 += 32) {
            s16x8 av[2], bv[4];
#pragma unroll
            for (int t = 0; t < 2; ++t)
                av[t] = *(const s16x8*)(&Zm[(p1i + t * 16 + l15) * PSTR + k0 + q * 8]);
#pragma unroll
            for (int ct = 0; ct < 4; ++ct)
                bv[ct] = *(const s16x8*)(&Yhi[(p1j + ct * 16 + l15) * PSTR + k0 + q * 8]);
#pragma unroll
            for (int rt = 0; rt < 2; ++rt)
#pragma unroll
                for (int ct = 0; ct < 4; ++ct)
                    acc4[rt][ct] = MF(av[rt], bv[ct], acc4[rt][ct]);
        }
        // write D (transposed-packed); D is not a P1 operand -> no pre-barrier
#pragma unroll
        for (int rt = 0; rt < 2; ++rt)
#pragma unroll
            for (int ct = 0; ct < 4; ++ct) {
                const int m0 = p1i + rt * 16 + q * 4;
                const int n  = p1j + ct * 16 + l15;
                s16x4 dv;
#pragma unroll
                for (int r = 0; r < 4; ++r) {
                    const float dia = (m0 + r == n) ? 0.5f : 0.0f;
                    dv[r] = (short)f2b(dia - 0.5f * acc4[rt][ct][r]);
                }
                *(s16x4*)(&Dm[n * PSTR + m0]) = dv;
            }
        __syncthreads();

        // ---- P2 (waves 0-3) || P3 (waves 4-7) ----
#pragma unroll
        for (int rt = 0; rt < 2; ++rt)
#pragma unroll
            for (int ct = 0; ct < 8; ++ct) acc8[rt][ct] = (f32x4){0.f, 0.f, 0.f, 0.f};

        if (it < 5) {
            if (half == 0) {
                // Ynew = Y + Y@D (dual split A)
#pragma unroll
                for (int k0 = 0; k0 < 128; k0 += 32) {
                    s16x8 ah[2], al[2], bv[8];
#pragma unroll
                    for (int t = 0; t < 2; ++t) {
                        ah[t] = *(const s16x8*)(&Yhi[(ri0 + t * 16 + l15) * PSTR + k0 + q * 8]);
                        al[t] = *(const s16x8*)(&Ylo[(ri0 + t * 16 + l15) * PSTR + k0 + q * 8]);
                    }
#pragma unroll
                    for (int ct = 0; ct < 8; ++ct)
                        bv[ct] = *(const s16x8*)(&Dm[(ct * 16 + l15) * PSTR + k0 + q * 8]);
#pragma unroll
                    for (int rt = 0; rt < 2; ++rt)
#pragma unroll
                        for (int ct = 0; ct < 8; ++ct) {
                            acc8[rt][ct] = MF(ah[rt], bv[ct], acc8[rt][ct]);
                            acc8[rt][ct] = MF(al[rt], bv[ct], acc8[rt][ct]);
                        }
                }
            } else {
                // Znew = Z + D@Z
#pragma unroll
                for (int k0 = 0; k0 < 128; k0 += 32) {
                    s16x8 av[2], bv[8];
#pragma unroll
                    for (int t = 0; t < 2; ++t)
                        av[t] = *(const s16x8*)(&Dm[(ri0 + t * 16 + l15) * PSTR + k0 + q * 8]);
#pragma unroll
                    for (int ct = 0; ct < 8; ++ct)
                        bv[ct] = *(const s16x8*)(&Zm[(ct * 16 + l15) * PSTR + k0 + q * 8]);
#pragma unroll
                    for (int rt = 0; rt < 2; ++rt)
#pragma unroll
                        for (int ct = 0; ct < 8; ++ct)
                            acc8[rt][ct] = MF(av[rt], bv[ct], acc8[rt][ct]);
                }
            }
            __syncthreads();   // all plane reads done before rewrites
#pragma unroll
            for (int rt = 0; rt < 2; ++rt)
#pragma unroll
                for (int ct = 0; ct < 8; ++ct) {
                    const int m0 = ri0 + rt * 16 + q * 4;
                    const int n  = ct * 16 + l15;
                    const int off = n * PSTR + m0;
                    if (half == 0) {
                        s16x4 nh, nl;
#pragma unroll
                        for (int r = 0; r < 4; ++r) {
                            const float y = c_reg[rt][ct][r] + acc8[rt][ct][r];
                            c_reg[rt][ct][r] = y;
                            unsigned short hh = f2b(y);
                            nh[r] = (short)hh;
                            nl[r] = (short)f2b(y - b2f(hh));
                        }
                        *(s16x4*)(&Yhi[off]) = nh;
                        *(s16x4*)(&Ylo[off]) = nl;
                    } else {
                        s16x4 zn;
#pragma unroll
                        for (int r = 0; r < 4; ++r) {
                            const float z = c_reg[rt][ct][r] + acc8[rt][ct][r];
                            c_reg[rt][ct][r] = z;
                            zn[r] = (short)f2b(z);
                        }
                        *(s16x4*)(&Zm[off]) = zn;
                    }
                }
            __syncthreads();
        } else {
            // final: P2 by waves 0-3; out = triu(Y + Y@D) * sqrt(tr)
            if (half == 0) {
#pragma unroll
                for (int k0 = 0; k0 < 128; k0 += 32) {
                    s16x8 ah[2], al[2], bv[8];
#pragma unroll
                    for (int t = 0; t < 2; ++t) {
                        ah[t] = *(const s16x8*)(&Yhi[(ri0 + t * 16 + l15) * PSTR + k0 + q * 8]);
                        al[t] = *(const s16x8*)(&Ylo[(ri0 + t * 16 + l15) * PSTR + k0 + q * 8]);
                    }
#pragma unroll
                    for (int ct = 0; ct < 8; ++ct)
                        bv[ct] = *(const s16x8*)(&Dm[(ct * 16 + l15) * PSTR + k0 + q * 8]);
#pragma unroll
                    for (int rt = 0; rt < 2; ++rt)
#pragma unroll
                        for (int ct = 0; ct < 8; ++ct) {
                            acc8[rt][ct] = MF(ah[rt], bv[ct], acc8[rt][ct]);
                            acc8[rt][ct] = MF(al[rt], bv[ct], acc8[rt][ct]);
                        }
                }
                float* __restrict__ ob = out + (size_t)b * OUTLEN;
#pragma unroll
                for (int rt = 0; rt < 2; ++rt)
#pragma unroll
                    for (int ct = 0; ct < 8; ++ct) {
                        const int m0 = ri0 + rt * 16 + q * 4;
                        const int n  = ct * 16 + l15;
#pragma unroll
                        for (int r = 0; r < 4; ++r) {
                            const int m = m0 + r;
                            if (m <= n) {
                                const float y = c_reg[rt][ct][r] + acc8[rt][ct][r];
                                ob[m * CC - ((m * (m - 1)) >> 1) + (n - m)] = y * sscale;
                            }
                        }
                    }
            }
        }
    }
}

extern "C" void kernel_launch(void* const* d_in, const int* in_sizes, int n_in,
                              void* d_out, int out_size, void* d_ws, size_t ws_size,
                              hipStream_t stream)
{
    (void)in_sizes; (void)n_in; (void)out_size; (void)ws_size;
    const float* x = (const float*)d_in[0];
    float* out = (float*)d_out;
    float* ws  = (float*)d_ws;

    float* trpart = ws;                                   // 256 floats
    float* rspart = ws + 256;                             // KS*BB*CC floats
    float* Gpart  = rspart + (size_t)KS * BB * CC;        // KS*BB*MATS floats
    short* Shi    = (short*)(Gpart + (size_t)KS * BB * MATS);  // BB*MATS shorts
    short* Slo    = Shi + (size_t)BB * MATS;                   // BB*MATS shorts

    gram_kernel<<<dim3(BB, KS), 256, 0, stream>>>(x, Gpart, rspart);
    reduce_kernel<<<dim3(BB, 4), 256, 0, stream>>>(Gpart, rspart, Shi, Slo, trpart);
    ns_kernel<<<dim3(BB), 512, 0, stream>>>(Shi, Slo, trpart, out);
}

// Round 7
// 197.112 us; speedup vs baseline: 1.0432x; 1.0432x over previous
//
#include <hip/hip_runtime.h>
#include <math.h>

// iSQRT-COV: B=64, C=128, n=3136.
// 1) gram: Gpart[ks] = X-chunk @ X-chunk^T via split-bf16 MFMA (448 blocks,
//    64-col double-buffered iterations -> 128 B/thread in flight)
// 2) reduce: sigma = sum(Gpart)/n - mu mu^T -> split-bf16 planes + tr partials
// 3) ns: fused Newton-Schulz, 64 blocks x 512 threads (8 waves, 2/SIMD).

#define CC 128
#define NN 3136
#define BB 64
#define KS 7
#define KCHUNK 448            // NN/KS = 7 iterations of 64 cols
#define MATS (CC * CC)
#define OUTLEN 8256
#define PSTR 136              // ns plane row stride in bf16
#define SSTR 66               // gram stage row stride in bf16 (33 dwords, odd)

typedef float f32x4 __attribute__((ext_vector_type(4)));
typedef short s16x8 __attribute__((ext_vector_type(8)));
typedef short s16x4 __attribute__((ext_vector_type(4)));
typedef __bf16 bf16x8 __attribute__((ext_vector_type(8)));

__device__ __forceinline__ unsigned short f2b(float f) {
    unsigned u = __builtin_bit_cast(unsigned, f);
    unsigned r = u + 0x7fffu + ((u >> 16) & 1u);
    return (unsigned short)(r >> 16);
}
__device__ __forceinline__ float b2f(unsigned short s) {
    return __builtin_bit_cast(float, ((unsigned)s) << 16);
}

__device__ __forceinline__ f32x4 MF(s16x8 a, s16x8 b, f32x4 c) {
    return __builtin_amdgcn_mfma_f32_16x16x32_bf16(
        __builtin_bit_cast(bf16x8, a), __builtin_bit_cast(bf16x8, b), c, 0, 0, 0);
}

// ---------------------------------------------------------------------------
// Gram partial. grid (BB, KS), block 256 (4 waves). 64 cols per iteration,
// double-buffered: 8 float4/thread in flight, 7 barriers total.
// ---------------------------------------------------------------------------
__global__ __launch_bounds__(256, 1)
void gram_kernel(const float* __restrict__ x, float* __restrict__ Gpart,
                 float* __restrict__ rspart)
{
    __shared__ short Xs[2][2][128 * SSTR];   // [buf][hi/lo][row*SSTR+col]
    const int b = blockIdx.x, ks = blockIdx.y;
    const int tid  = threadIdx.x;
    const int wave = tid >> 6, lane = tid & 63;
    const int q = lane >> 4, l15 = lane & 15;
    const int i0 = (wave >> 1) * 64, j0 = (wave & 1) * 64;

    const float* __restrict__ Xb = x + (size_t)b * CC * NN + (size_t)ks * KCHUNK;
    const int lrow = tid >> 3;        // 0..31
    const int lc   = (tid & 7) * 8;   // 0,8,..,56 (col base, 2 float4s)

    f32x4 acc[4][4];
#pragma unroll
    for (int rt = 0; rt < 4; ++rt)
#pragma unroll
        for (int ct = 0; ct < 4; ++ct) acc[rt][ct] = (f32x4){0.f, 0.f, 0.f, 0.f};
    float rs[4] = {0.f, 0.f, 0.f, 0.f};

    float4 ld[4][2];
#pragma unroll
    for (int p = 0; p < 4; ++p) {
        const float* row = Xb + (size_t)(lrow + 32 * p) * NN + lc;
        ld[p][0] = *(const float4*)(row);
        ld[p][1] = *(const float4*)(row + 4);
    }

    // convert + write buf 0
#pragma unroll
    for (int p = 0; p < 4; ++p) {
        const int off = (lrow + 32 * p) * SSTR + lc;
#pragma unroll
        for (int h = 0; h < 2; ++h) {
            const float4 v = ld[p][h];
            rs[p] += v.x + v.y + v.z + v.w;
            float f[4] = {v.x, v.y, v.z, v.w};
            s16x4 hh, ll;
#pragma unroll
            for (int r = 0; r < 4; ++r) {
                unsigned short hb = f2b(f[r]);
                hh[r] = (short)hb;
                ll[r] = (short)f2b(f[r] - b2f(hb));
            }
            *(s16x4*)(&Xs[0][0][off + 4 * h]) = hh;
            *(s16x4*)(&Xs[0][1][off + 4 * h]) = ll;
        }
    }
    __syncthreads();

    for (int it = 0; it < 7; ++it) {
        const int cur = it & 1;
        if (it < 6) {
#pragma unroll
            for (int p = 0; p < 4; ++p) {
                const float* row = Xb + (size_t)(lrow + 32 * p) * NN + (it + 1) * 64 + lc;
                ld[p][0] = *(const float4*)(row);
                ld[p][1] = *(const float4*)(row + 4);
            }
        }
        // MFMA on buf cur: two ksteps of 32
#pragma unroll
        for (int kk = 0; kk < 2; ++kk) {
            s16x8 ah[4], al[4], bh[4], bl[4];
#pragma unroll
            for (int t = 0; t < 4; ++t) {
                const int ra = (i0 + t * 16 + l15) * SSTR + kk * 32 + q * 8;
                const int rb = (j0 + t * 16 + l15) * SSTR + kk * 32 + q * 8;
                ah[t] = *(const s16x8*)(&Xs[cur][0][ra]);
                al[t] = *(const s16x8*)(&Xs[cur][1][ra]);
                bh[t] = *(const s16x8*)(&Xs[cur][0][rb]);
                bl[t] = *(const s16x8*)(&Xs[cur][1][rb]);
            }
#pragma unroll
            for (int rt = 0; rt < 4; ++rt)
#pragma unroll
                for (int ct = 0; ct < 4; ++ct) {
                    acc[rt][ct] = MF(ah[rt], bh[ct], acc[rt][ct]);
                    acc[rt][ct] = MF(ah[rt], bl[ct], acc[rt][ct]);
                    acc[rt][ct] = MF(al[rt], bh[ct], acc[rt][ct]);
                }
        }
        if (it < 6) {
#pragma unroll
            for (int p = 0; p < 4; ++p) {
                const int off = (lrow + 32 * p) * SSTR + lc;
#pragma unroll
                for (int h = 0; h < 2; ++h) {
                    const float4 v = ld[p][h];
                    rs[p] += v.x + v.y + v.z + v.w;
                    float f[4] = {v.x, v.y, v.z, v.w};
                    s16x4 hh, ll;
#pragma unroll
                    for (int r = 0; r < 4; ++r) {
                        unsigned short hb = f2b(f[r]);
                        hh[r] = (short)hb;
                        ll[r] = (short)f2b(f[r] - b2f(hb));
                    }
                    *(s16x4*)(&Xs[cur ^ 1][0][off + 4 * h]) = hh;
                    *(s16x4*)(&Xs[cur ^ 1][1][off + 4 * h]) = ll;
                }
            }
            __syncthreads();
        }
    }

    float* __restrict__ Gb = Gpart + (size_t)(ks * BB + b) * MATS;
#pragma unroll
    for (int rt = 0; rt < 4; ++rt)
#pragma unroll
        for (int ct = 0; ct < 4; ++ct)
#pragma unroll
            for (int r = 0; r < 4; ++r) {
                const int m = i0 + rt * 16 + q * 4 + r;
                const int n = j0 + ct * 16 + l15;
                Gb[m * CC + n] = acc[rt][ct][r];
            }
#pragma unroll
    for (int p = 0; p < 4; ++p) {
        float v = rs[p];
        v += __shfl_xor(v, 1);
        v += __shfl_xor(v, 2);
        v += __shfl_xor(v, 4);
        if ((lane & 7) == 0)
            rspart[(size_t)(ks * BB + b) * CC + lrow + 32 * p] = v;
    }
}

// ---------------------------------------------------------------------------
// Reduce: sigma = sum_ks(Gpart)/n - mu mu^T -> split-bf16 planes + tr partials.
// grid (BB, 4), block 256.
// ---------------------------------------------------------------------------
__global__ __launch_bounds__(256, 2)
void reduce_kernel(const float* __restrict__ Gpart, const float* __restrict__ rspart,
                   short* __restrict__ Shi, short* __restrict__ Slo,
                   float* __restrict__ trpart)
{
    __shared__ float mu[CC];
    __shared__ float red[256];
    const int b = blockIdx.x, qr = blockIdx.y;
    const int tid = threadIdx.x;

    if (tid < CC) {
        float s = 0.f;
#pragma unroll
        for (int ks = 0; ks < KS; ++ks)
            s += rspart[(size_t)(ks * BB + b) * CC + tid];
        mu[tid] = s * (1.0f / NN);
    }
    __syncthreads();

    const float4* __restrict__ GP4 = (const float4*)Gpart;
    float trsum = 0.f;
#pragma unroll
    for (int j = 0; j < 4; ++j) {
        const int idx4 = qr * 1024 + tid + 256 * j;
        float4 tb[KS];
#pragma unroll
        for (int ks = 0; ks < KS; ++ks)
            tb[ks] = GP4[(size_t)(ks * BB + b) * 4096 + idx4];
        const int row = idx4 >> 5;
        const int c4  = (idx4 & 31) << 2;
        float g[4] = {0.f, 0.f, 0.f, 0.f};
#pragma unroll
        for (int ks = 0; ks < KS; ++ks) {
            g[0] += tb[ks].x; g[1] += tb[ks].y;
            g[2] += tb[ks].z; g[3] += tb[ks].w;
        }
        const float mr = mu[row];
        s16x4 h, l;
#pragma unroll
        for (int r = 0; r < 4; ++r) {
            const float s = g[r] * (1.0f / NN) - mr * mu[c4 + r];
            unsigned short hh = f2b(s);
            h[r] = (short)hh;
            l[r] = (short)f2b(s - b2f(hh));
            if (row == c4 + r) trsum += s;
        }
        *(s16x4*)(Shi + (size_t)b * MATS + idx4 * 4) = h;
        *(s16x4*)(Slo + (size_t)b * MATS + idx4 * 4) = l;
    }
    red[tid] = trsum;
    __syncthreads();
    for (int s = 128; s > 0; s >>= 1) {
        if (tid < s) red[tid] += red[tid + s];
        __syncthreads();
    }
    if (tid == 0) trpart[b * 4 + qr] = red[0];
}

// ---------------------------------------------------------------------------
// Fused NS: 512 threads (8 waves, 2/SIMD). P1 (D=0.5I-0.5*Z@Y) on all 8 waves
// (32x64 tiles); P2 (Y+=Y@D, waves 0-3) and P3 (Z+=D@Z, waves 4-7) run
// concurrently on 32x128 strips. Y,Z fp32 in regs of their wave group.
// All NS matrices symmetric -> transposed packed LDS writes valid.
// ---------------------------------------------------------------------------
__global__ __launch_bounds__(512, 2)
void ns_kernel(const short* __restrict__ Shi, const short* __restrict__ Slo,
               const float* __restrict__ trpart, float* __restrict__ out)
{
    __shared__ short Yhi[128 * PSTR];
    __shared__ short Ylo[128 * PSTR];
    __shared__ short Dm [128 * PSTR];
    __shared__ short Zm [128 * PSTR];

    const int b = blockIdx.x;
    const int tid  = threadIdx.x;
    const int wave = tid >> 6, lane = tid & 63;
    const int q = lane >> 4, l15 = lane & 15;

    const float tr = trpart[b * 4 + 0] + trpart[b * 4 + 1] +
                     trpart[b * 4 + 2] + trpart[b * 4 + 3];
    const float invtr = 1.0f / tr;
    const float sscale = sqrtf(tr);

    // ---- planes: Y1 = A = sigma/tr (split), D1 = 0.5I-0.5A, Z1 = I+D1 ----
#pragma unroll
    for (int jj = 0; jj < 8; ++jj) {
        const int idx4 = tid + 512 * jj;
        const int row = idx4 >> 5;
        const int c4  = (idx4 & 31) << 2;
        const s16x4 sh = *(const s16x4*)(Shi + (size_t)b * MATS + idx4 * 4);
        const s16x4 sl = *(const s16x4*)(Slo + (size_t)b * MATS + idx4 * 4);
        s16x4 yh, yl, dv, zv;
#pragma unroll
        for (int r = 0; r < 4; ++r) {
            const float a = (b2f((unsigned short)sh[r]) + b2f((unsigned short)sl[r])) * invtr;
            unsigned short hh = f2b(a);
            yh[r] = (short)hh;
            yl[r] = (short)f2b(a - b2f(hh));
            const float dia = (row == c4 + r) ? 0.5f : 0.0f;
            const float d = dia - 0.5f * a;
            dv[r] = (short)f2b(d);
            zv[r] = (short)f2b(((row == c4 + r) ? 1.0f : 0.0f) + d);
        }
        const int off = row * PSTR + c4;
        *(s16x4*)(&Yhi[off]) = yh;
        *(s16x4*)(&Ylo[off]) = yl;
        *(s16x4*)(&Dm[off])  = dv;
        *(s16x4*)(&Zm[off])  = zv;
    }
    __syncthreads();

    const int half = wave >> 2;     // 0: Y-group (P2), 1: Z-group (P3)
    const int w    = wave & 3;
    const int ri0  = w * 32;        // strip row base for P2/P3
    const int p1i  = (wave >> 1) * 32;   // P1 tile coords
    const int p1j  = (wave & 1) * 64;

    // ---- fp32 carry at this wave's strip frag positions ----
    f32x4 c_reg[2][8];
#pragma unroll
    for (int rt = 0; rt < 2; ++rt)
#pragma unroll
        for (int ct = 0; ct < 8; ++ct) {
            const int m0 = ri0 + rt * 16 + q * 4;
            const int n  = ct * 16 + l15;
            const int off = n * PSTR + m0;
            if (half == 0) {
                s16x4 yh = *(s16x4*)(&Yhi[off]);
                s16x4 yl = *(s16x4*)(&Ylo[off]);
#pragma unroll
                for (int r = 0; r < 4; ++r)
                    c_reg[rt][ct][r] = b2f((unsigned short)yh[r]) + b2f((unsigned short)yl[r]);
            } else {
                s16x4 zv = *(s16x4*)(&Zm[off]);
#pragma unroll
                for (int r = 0; r < 4; ++r)
                    c_reg[rt][ct][r] = b2f((unsigned short)zv[r]);
            }
        }

    f32x4 acc8[2][8];

    // ================= it1: P2 only (Y2 = Y1 + Y1@D1; Z1 already = T1) =====
#pragma unroll
    for (int rt = 0; rt < 2; ++rt)
#pragma unroll
        for (int ct = 0; ct < 8; ++ct) acc8[rt][ct] = (f32x4){0.f, 0.f, 0.f, 0.f};
    if (half == 0) {
#pragma unroll
        for (int k0 = 0; k0 < 128; k0 += 32) {
            s16x8 ah[2], al[2], bv[8];
#pragma unroll
            for (int t = 0; t < 2; ++t) {
                ah[t] = *(const s16x8*)(&Yhi[(ri0 + t * 16 + l15) * PSTR + k0 + q * 8]);
                al[t] = *(const s16x8*)(&Ylo[(ri0 + t * 16 + l15) * PSTR + k0 + q * 8]);
            }
#pragma unroll
            for (int ct = 0; ct < 8; ++ct)
                bv[ct] = *(const s16x8*)(&Dm[(ct * 16 + l15) * PSTR + k0 + q * 8]);
#pragma unroll
            for (int rt = 0; rt < 2; ++rt)
#pragma unroll
                for (int ct = 0; ct < 8; ++ct) {
                    acc8[rt][ct] = MF(ah[rt], bv[ct], acc8[rt][ct]);
                    acc8[rt][ct] = MF(al[rt], bv[ct], acc8[rt][ct]);
                }
        }
    }
    __syncthreads();
    if (half == 0) {
#pragma unroll
        for (int rt = 0; rt < 2; ++rt)
#pragma unroll
            for (int ct = 0; ct < 8; ++ct) {
                const int m0 = ri0 + rt * 16 + q * 4;
                const int n  = ct * 16 + l15;
                const int off = n * PSTR + m0;
                s16x4 nh, nl;
#pragma unroll
                for (int r = 0; r < 4; ++r) {
                    const float y = c_reg[rt][ct][r] + acc8[rt][ct][r];
                    c_reg[rt][ct][r] = y;
                    unsigned short hh = f2b(y);
                    nh[r] = (short)hh;
                    nl[r] = (short)f2b(y - b2f(hh));
                }
                *(s16x4*)(&Yhi[off]) = nh;
                *(s16x4*)(&Ylo[off]) = nl;
            }
    }
    __syncthreads();

    // ================= it2..5 =================
    for (int it = 2; it <= 5; ++it) {
        // ---- P1 (all 8 waves): D = 0.5I - 0.5 * Z@Y (Y ~ Yhi) ----
        f32x4 acc4[2][4];
#pragma unroll
        for (int rt = 0; rt < 2; ++rt)
#pragma unroll
            for (int ct = 0; ct < 4; ++ct) acc4[rt][ct] = (f32x4){0.f, 0.f, 0.f, 0.f};
#pragma unroll
        for (int k0 = 0; k0 < 128; k0 += 32) {
            s16x8 av[2], bv[4];
#pragma unroll
            for (int t = 0; t < 2; ++t)
                av[t] = *(const s16x8*)(&Zm[(p1i + t * 16 + l15) * PSTR + k0 + q * 8]);
#pragma unroll
            for (int ct = 0; ct < 4; ++ct)
                bv[ct] = *(const s16x8*)(&Yhi[(p1j + ct * 16 + l15) * PSTR + k0 + q * 8]);
#pragma unroll
            for (int rt = 0; rt < 2; ++rt)
#pragma unroll
                for (int ct = 0; ct < 4; ++ct)
                    acc4[rt][ct] = MF(av[rt], bv[ct], acc4[rt][ct]);
        }
        // write D (transposed-packed); D is not a P1 operand -> no pre-barrier
#pragma unroll
        for (int rt = 0; rt < 2; ++rt)
#pragma unroll
            for (int ct = 0; ct < 4; ++ct) {
                const int m0 = p1i + rt * 16 + q * 4;
                const int n  = p1j + ct * 16 + l15;
                s16x4 dv;
#pragma unroll
                for (int r = 0; r < 4; ++r) {
                    const float dia = (m0 + r == n) ? 0.5f : 0.0f;
                    dv[r] = (short)f2b(dia - 0.5f * acc4[rt][ct][r]);
                }
                *(s16x4*)(&Dm[n * PSTR + m0]) = dv;
            }
        __syncthreads();

        // ---- P2 (waves 0-3) || P3 (waves 4-7) ----
#pragma unroll
        for (int rt = 0; rt < 2; ++rt)
#pragma unroll
            for (int ct = 0; ct < 8; ++ct) acc8[rt][ct] = (f32x4){0.f, 0.f, 0.f, 0.f};

        if (it < 5) {
            if (half == 0) {
                // Ynew = Y + Y@D (dual split A)
#pragma unroll
                for (int k0 = 0; k0 < 128; k0 += 32) {
                    s16x8 ah[2], al[2], bv[8];
#pragma unroll
                    for (int t = 0; t < 2; ++t) {
                        ah[t] = *(const s16x8*)(&Yhi[(ri0 + t * 16 + l15) * PSTR + k0 + q * 8]);
                        al[t] = *(const s16x8*)(&Ylo[(ri0 + t * 16 + l15) * PSTR + k0 + q * 8]);
                    }
#pragma unroll
                    for (int ct = 0; ct < 8; ++ct)
                        bv[ct] = *(const s16x8*)(&Dm[(ct * 16 + l15) * PSTR + k0 + q * 8]);
#pragma unroll
                    for (int rt = 0; rt < 2; ++rt)
#pragma unroll
                        for (int ct = 0; ct < 8; ++ct) {
                            acc8[rt][ct] = MF(ah[rt], bv[ct], acc8[rt][ct]);
                            acc8[rt][ct] = MF(al[rt], bv[ct], acc8[rt][ct]);
                        }
                }
            } else {
                // Znew = Z + D@Z
#pragma unroll
                for (int k0 = 0; k0 < 128; k0 += 32) {
                    s16x8 av[2], bv[8];
#pragma unroll
                    for (int t = 0; t < 2; ++t)
                        av[t] = *(const s16x8*)(&Dm[(ri0 + t * 16 + l15) * PSTR + k0 + q * 8]);
#pragma unroll
                    for (int ct = 0; ct < 8; ++ct)
                        bv[ct] = *(const s16x8*)(&Zm[(ct * 16 + l15) * PSTR + k0 + q * 8]);
#pragma unroll
                    for (int rt = 0; rt < 2; ++rt)
#pragma unroll
                        for (int ct = 0; ct < 8; ++ct)
                            acc8[rt][ct] = MF(av[rt], bv[ct], acc8[rt][ct]);
                }
            }
            __syncthreads();   // all plane reads done before rewrites
#pragma unroll
            for (int rt = 0; rt < 2; ++rt)
#pragma unroll
                for (int ct = 0; ct < 8; ++ct) {
                    const int m0 = ri0 + rt * 16 + q * 4;
                    const int n  = ct * 16 + l15;
                    const int off = n * PSTR + m0;
                    if (half == 0) {
                        s16x4 nh, nl;
#pragma unroll
                        for (int r = 0; r < 4; ++r) {
                            const float y = c_reg[rt][ct][r] + acc8[rt][ct][r];
                            c_reg[rt][ct][r] = y;
                            unsigned short hh = f2b(y);
                            nh[r] = (short)hh;
                            nl[r] = (short)f2b(y - b2f(hh));
                        }
                        *(s16x4*)(&Yhi[off]) = nh;
                        *(s16x4*)(&Ylo[off]) = nl;
                    } else {
                        s16x4 zn;
#pragma unroll
                        for (int r = 0; r < 4; ++r) {
                            const float z = c_reg[rt][ct][r] + acc8[rt][ct][r];
                            c_reg[rt][ct][r] = z;
                            zn[r] = (short)f2b(z);
                        }
                        *(s16x4*)(&Zm[off]) = zn;
                    }
                }
            __syncthreads();
        } else {
            // final: P2 by waves 0-3; out = triu(Y + Y@D) * sqrt(tr)
            if (half == 0) {
#pragma unroll
                for (int k0 = 0; k0 < 128; k0 += 32) {
                    s16x8 ah[2], al[2], bv[8];
#pragma unroll
                    for (int t = 0; t < 2; ++t) {
                        ah[t] = *(const s16x8*)(&Yhi[(ri0 + t * 16 + l15) * PSTR + k0 + q * 8]);
                        al[t] = *(const s16x8*)(&Ylo[(ri0 + t * 16 + l15) * PSTR + k0 + q * 8]);
                    }
#pragma unroll
                    for (int ct = 0; ct < 8; ++ct)
                        bv[ct] = *(const s16x8*)(&Dm[(ct * 16 + l15) * PSTR + k0 + q * 8]);
#pragma unroll
                    for (int rt = 0; rt < 2; ++rt)
#pragma unroll
                        for (int ct = 0; ct < 8; ++ct) {
                            acc8[rt][ct] = MF(ah[rt], bv[ct], acc8[rt][ct]);
                            acc8[rt][ct] = MF(al[rt], bv[ct], acc8[rt][ct]);
                        }
                }
                float* __restrict__ ob = out + (size_t)b * OUTLEN;
#pragma unroll
                for (int rt = 0; rt < 2; ++rt)
#pragma unroll
                    for (int ct = 0; ct < 8; ++ct) {
                        const int m0 = ri0 + rt * 16 + q * 4;
                        const int n  = ct * 16 + l15;
#pragma unroll
                        for (int r = 0; r < 4; ++r) {
                            const int m = m0 + r;
                            if (m <= n) {
                                const float y = c_reg[rt][ct][r] + acc8[rt][ct][r];
                                ob[m * CC - ((m * (m - 1)) >> 1) + (n - m)] = y * sscale;
                            }
                        }
                    }
            }
        }
    }
}

extern "C" void kernel_launch(void* const* d_in, const int* in_sizes, int n_in,
                              void* d_out, int out_size, void* d_ws, size_t ws_size,
                              hipStream_t stream)
{
    (void)in_sizes; (void)n_in; (void)out_size; (void)ws_size;
    const float* x = (const float*)d_in[0];
    float* out = (float*)d_out;
    float* ws  = (float*)d_ws;

    float* trpart = ws;                                   // 256 floats
    float* rspart = ws + 256;                             // KS*BB*CC floats
    float* Gpart  = rspart + (size_t)KS * BB * CC;        // KS*BB*MATS floats
    short* Shi    = (short*)(Gpart + (size_t)KS * BB * MATS);  // BB*MATS shorts
    short* Slo    = Shi + (size_t)BB * MATS;                   // BB*MATS shorts

    gram_kernel<<<dim3(BB, KS), 256, 0, stream>>>(x, Gpart, rspart);
    reduce_kernel<<<dim3(BB, 4), 256, 0, stream>>>(Gpart, rspart, Shi, Slo, trpart);
    ns_kernel<<<dim3(BB), 512, 0, stream>>>(Shi, Slo, trpart, out);
}

// Round 8
// 185.535 us; speedup vs baseline: 1.1083x; 1.0624x over previous
//
#include <hip/hip_runtime.h>
#include <math.h>

// iSQRT-COV: B=64, C=128, n=3136.
// 1) gram: Gpart[ks] = X-chunk @ X-chunk^T via split-bf16 MFMA (448 blocks)
// 2) reduce: sigma = sum(Gpart)/n - mu mu^T -> split-bf16 planes + tr partials
// 3) ns: fused Newton-Schulz, 64 blocks x 1024 threads (16 waves, 4/SIMD),
//    XOR-swizzled LDS planes (bank-conflict-free), P2||P3 wave split.

#define CC 128
#define NN 3136
#define BB 64
#define KS 7
#define KCHUNK 448            // NN/KS = 7 iterations of 64 cols
#define MATS (CC * CC)
#define OUTLEN 8256
#define SSTR 66               // gram stage row stride in bf16 (33 dwords, odd)

// ns plane addressing: row n, short-index ks in [0,128); 16B-granule XOR swizzle
#define NSW(n, ks) (((n) << 7) + (((((ks) >> 3) ^ ((n) & 15)) << 3) | ((ks) & 7)))

typedef float f32x4 __attribute__((ext_vector_type(4)));
typedef short s16x8 __attribute__((ext_vector_type(8)));
typedef short s16x4 __attribute__((ext_vector_type(4)));
typedef __bf16 bf16x8 __attribute__((ext_vector_type(8)));

__device__ __forceinline__ unsigned short f2b(float f) {
    unsigned u = __builtin_bit_cast(unsigned, f);
    unsigned r = u + 0x7fffu + ((u >> 16) & 1u);
    return (unsigned short)(r >> 16);
}
__device__ __forceinline__ float b2f(unsigned short s) {
    return __builtin_bit_cast(float, ((unsigned)s) << 16);
}

__device__ __forceinline__ f32x4 MF(s16x8 a, s16x8 b, f32x4 c) {
    return __builtin_amdgcn_mfma_f32_16x16x32_bf16(
        __builtin_bit_cast(bf16x8, a), __builtin_bit_cast(bf16x8, b), c, 0, 0, 0);
}

// ---------------------------------------------------------------------------
// Gram partial. grid (BB, KS), block 256 (4 waves). 64 cols per iteration,
// double-buffered: 8 float4/thread in flight, 7 barriers total.
// ---------------------------------------------------------------------------
__global__ __launch_bounds__(256, 1)
void gram_kernel(const float* __restrict__ x, float* __restrict__ Gpart,
                 float* __restrict__ rspart)
{
    __shared__ short Xs[2][2][128 * SSTR];   // [buf][hi/lo][row*SSTR+col]
    const int b = blockIdx.x, ks = blockIdx.y;
    const int tid  = threadIdx.x;
    const int wave = tid >> 6, lane = tid & 63;
    const int q = lane >> 4, l15 = lane & 15;
    const int i0 = (wave >> 1) * 64, j0 = (wave & 1) * 64;

    const float* __restrict__ Xb = x + (size_t)b * CC * NN + (size_t)ks * KCHUNK;
    const int lrow = tid >> 3;        // 0..31
    const int lc   = (tid & 7) * 8;   // 0,8,..,56

    f32x4 acc[4][4];
#pragma unroll
    for (int rt = 0; rt < 4; ++rt)
#pragma unroll
        for (int ct = 0; ct < 4; ++ct) acc[rt][ct] = (f32x4){0.f, 0.f, 0.f, 0.f};
    float rs[4] = {0.f, 0.f, 0.f, 0.f};

    float4 ld[4][2];
#pragma unroll
    for (int p = 0; p < 4; ++p) {
        const float* row = Xb + (size_t)(lrow + 32 * p) * NN + lc;
        ld[p][0] = *(const float4*)(row);
        ld[p][1] = *(const float4*)(row + 4);
    }

#pragma unroll
    for (int p = 0; p < 4; ++p) {
        const int off = (lrow + 32 * p) * SSTR + lc;
#pragma unroll
        for (int h = 0; h < 2; ++h) {
            const float4 v = ld[p][h];
            rs[p] += v.x + v.y + v.z + v.w;
            float f[4] = {v.x, v.y, v.z, v.w};
            s16x4 hh, ll;
#pragma unroll
            for (int r = 0; r < 4; ++r) {
                unsigned short hb = f2b(f[r]);
                hh[r] = (short)hb;
                ll[r] = (short)f2b(f[r] - b2f(hb));
            }
            *(s16x4*)(&Xs[0][0][off + 4 * h]) = hh;
            *(s16x4*)(&Xs[0][1][off + 4 * h]) = ll;
        }
    }
    __syncthreads();

    for (int it = 0; it < 7; ++it) {
        const int cur = it & 1;
        if (it < 6) {
#pragma unroll
            for (int p = 0; p < 4; ++p) {
                const float* row = Xb + (size_t)(lrow + 32 * p) * NN + (it + 1) * 64 + lc;
                ld[p][0] = *(const float4*)(row);
                ld[p][1] = *(const float4*)(row + 4);
            }
        }
#pragma unroll
        for (int kk = 0; kk < 2; ++kk) {
            s16x8 ah[4], al[4], bh[4], bl[4];
#pragma unroll
            for (int t = 0; t < 4; ++t) {
                const int ra = (i0 + t * 16 + l15) * SSTR + kk * 32 + q * 8;
                const int rb = (j0 + t * 16 + l15) * SSTR + kk * 32 + q * 8;
                ah[t] = *(const s16x8*)(&Xs[cur][0][ra]);
                al[t] = *(const s16x8*)(&Xs[cur][1][ra]);
                bh[t] = *(const s16x8*)(&Xs[cur][0][rb]);
                bl[t] = *(const s16x8*)(&Xs[cur][1][rb]);
            }
#pragma unroll
            for (int rt = 0; rt < 4; ++rt)
#pragma unroll
                for (int ct = 0; ct < 4; ++ct) {
                    acc[rt][ct] = MF(ah[rt], bh[ct], acc[rt][ct]);
                    acc[rt][ct] = MF(ah[rt], bl[ct], acc[rt][ct]);
                    acc[rt][ct] = MF(al[rt], bh[ct], acc[rt][ct]);
                }
        }
        if (it < 6) {
#pragma unroll
            for (int p = 0; p < 4; ++p) {
                const int off = (lrow + 32 * p) * SSTR + lc;
#pragma unroll
                for (int h = 0; h < 2; ++h) {
                    const float4 v = ld[p][h];
                    rs[p] += v.x + v.y + v.z + v.w;
                    float f[4] = {v.x, v.y, v.z, v.w};
                    s16x4 hh, ll;
#pragma unroll
                    for (int r = 0; r < 4; ++r) {
                        unsigned short hb = f2b(f[r]);
                        hh[r] = (short)hb;
                        ll[r] = (short)f2b(f[r] - b2f(hb));
                    }
                    *(s16x4*)(&Xs[cur ^ 1][0][off + 4 * h]) = hh;
                    *(s16x4*)(&Xs[cur ^ 1][1][off + 4 * h]) = ll;
                }
            }
            __syncthreads();
        }
    }

    float* __restrict__ Gb = Gpart + (size_t)(ks * BB + b) * MATS;
#pragma unroll
    for (int rt = 0; rt < 4; ++rt)
#pragma unroll
        for (int ct = 0; ct < 4; ++ct)
#pragma unroll
            for (int r = 0; r < 4; ++r) {
                const int m = i0 + rt * 16 + q * 4 + r;
                const int n = j0 + ct * 16 + l15;
                Gb[m * CC + n] = acc[rt][ct][r];
            }
#pragma unroll
    for (int p = 0; p < 4; ++p) {
        float v = rs[p];
        v += __shfl_xor(v, 1);
        v += __shfl_xor(v, 2);
        v += __shfl_xor(v, 4);
        if ((lane & 7) == 0)
            rspart[(size_t)(ks * BB + b) * CC + lrow + 32 * p] = v;
    }
}

// ---------------------------------------------------------------------------
// Reduce: sigma = sum_ks(Gpart)/n - mu mu^T -> split-bf16 planes + tr partials.
// grid (BB, 4), block 256.
// ---------------------------------------------------------------------------
__global__ __launch_bounds__(256, 2)
void reduce_kernel(const float* __restrict__ Gpart, const float* __restrict__ rspart,
                   short* __restrict__ Shi, short* __restrict__ Slo,
                   float* __restrict__ trpart)
{
    __shared__ float mu[CC];
    __shared__ float red[256];
    const int b = blockIdx.x, qr = blockIdx.y;
    const int tid = threadIdx.x;

    if (tid < CC) {
        float s = 0.f;
#pragma unroll
        for (int ks = 0; ks < KS; ++ks)
            s += rspart[(size_t)(ks * BB + b) * CC + tid];
        mu[tid] = s * (1.0f / NN);
    }
    __syncthreads();

    const float4* __restrict__ GP4 = (const float4*)Gpart;
    float trsum = 0.f;
#pragma unroll
    for (int j = 0; j < 4; ++j) {
        const int idx4 = qr * 1024 + tid + 256 * j;
        float4 tb[KS];
#pragma unroll
        for (int ks = 0; ks < KS; ++ks)
            tb[ks] = GP4[(size_t)(ks * BB + b) * 4096 + idx4];
        const int row = idx4 >> 5;
        const int c4  = (idx4 & 31) << 2;
        float g[4] = {0.f, 0.f, 0.f, 0.f};
#pragma unroll
        for (int ks = 0; ks < KS; ++ks) {
            g[0] += tb[ks].x; g[1] += tb[ks].y;
            g[2] += tb[ks].z; g[3] += tb[ks].w;
        }
        const float mr = mu[row];
        s16x4 h, l;
#pragma unroll
        for (int r = 0; r < 4; ++r) {
            const float s = g[r] * (1.0f / NN) - mr * mu[c4 + r];
            unsigned short hh = f2b(s);
            h[r] = (short)hh;
            l[r] = (short)f2b(s - b2f(hh));
            if (row == c4 + r) trsum += s;
        }
        *(s16x4*)(Shi + (size_t)b * MATS + idx4 * 4) = h;
        *(s16x4*)(Slo + (size_t)b * MATS + idx4 * 4) = l;
    }
    red[tid] = trsum;
    __syncthreads();
    for (int s = 128; s > 0; s >>= 1) {
        if (tid < s) red[tid] += red[tid + s];
        __syncthreads();
    }
    if (tid == 0) trpart[b * 4 + qr] = red[0];
}

// ---------------------------------------------------------------------------
// Fused NS: 1024 threads (16 waves, 4/SIMD). XOR-swizzled planes (PSTR=128).
// P1 (D = 0.5I - 0.5*Z@Y) on all 16 waves (32x32 tiles);
// P2 (Y += Y@D, waves 0-7) || P3 (Z += D@Z, waves 8-15), 16x128 strips.
// All NS matrices symmetric (polynomials of A, commute) -> transposed packed
// LDS writes are valid. Y split hi/lo bf16, D/Z single bf16 (damped paths).
// ---------------------------------------------------------------------------
__global__ __launch_bounds__(1024, 4)
void ns_kernel(const short* __restrict__ Shi, const short* __restrict__ Slo,
               const float* __restrict__ trpart, float* __restrict__ out)
{
    __shared__ short Yhi[MATS];
    __shared__ short Ylo[MATS];
    __shared__ short Dm [MATS];
    __shared__ short Zm [MATS];

    const int b = blockIdx.x;
    const int tid  = threadIdx.x;
    const int wave = tid >> 6, lane = tid & 63;
    const int q = lane >> 4, l15 = lane & 15;

    const float tr = trpart[b * 4 + 0] + trpart[b * 4 + 1] +
                     trpart[b * 4 + 2] + trpart[b * 4 + 3];
    const float invtr = 1.0f / tr;
    const float sscale = sqrtf(tr);

    // ---- planes: Y1 = A = sigma/tr (split), D1 = 0.5I-0.5A, Z1 = I+D1 ----
#pragma unroll
    for (int jj = 0; jj < 4; ++jj) {
        const int idx4 = tid + 1024 * jj;
        const int row = idx4 >> 5;
        const int c4  = (idx4 & 31) << 2;
        const s16x4 sh = *(const s16x4*)(Shi + (size_t)b * MATS + idx4 * 4);
        const s16x4 sl = *(const s16x4*)(Slo + (size_t)b * MATS + idx4 * 4);
        s16x4 yh, yl, dv, zv;
#pragma unroll
        for (int r = 0; r < 4; ++r) {
            const float a = (b2f((unsigned short)sh[r]) + b2f((unsigned short)sl[r])) * invtr;
            unsigned short hh = f2b(a);
            yh[r] = (short)hh;
            yl[r] = (short)f2b(a - b2f(hh));
            const float dia = (row == c4 + r) ? 0.5f : 0.0f;
            const float d = dia - 0.5f * a;
            dv[r] = (short)f2b(d);
            zv[r] = (short)f2b(((row == c4 + r) ? 1.0f : 0.0f) + d);
        }
        const int off = NSW(row, c4);
        *(s16x4*)(&Yhi[off]) = yh;
        *(s16x4*)(&Ylo[off]) = yl;
        *(s16x4*)(&Dm[off])  = dv;
        *(s16x4*)(&Zm[off])  = zv;
    }
    __syncthreads();

    const int half = wave >> 3;          // 0: Y-group (P2), 1: Z-group (P3)
    const int ri0  = (wave & 7) * 16;    // strip row base for P2/P3
    const int p1i  = (wave >> 2) * 32;   // P1 tile coords (4x4 grid of 32x32)
    const int p1j  = (wave & 3) * 32;

    f32x4 acc8[8];

    // ======== it1: P2 only (Y2 = Y1 + Y1@D1; Z1 already equals T1) ========
#pragma unroll
    for (int ct = 0; ct < 8; ++ct) acc8[ct] = (f32x4){0.f, 0.f, 0.f, 0.f};
    if (half == 0) {
#pragma unroll
        for (int k0 = 0; k0 < 128; k0 += 32) {
            const int ka = k0 + q * 8;
            s16x8 ah = *(const s16x8*)(&Yhi[NSW(ri0 + l15, ka)]);
            s16x8 al = *(const s16x8*)(&Ylo[NSW(ri0 + l15, ka)]);
            s16x8 bv[8];
#pragma unroll
            for (int ct = 0; ct < 8; ++ct)
                bv[ct] = *(const s16x8*)(&Dm[NSW(ct * 16 + l15, ka)]);
#pragma unroll
            for (int ct = 0; ct < 8; ++ct) {
                acc8[ct] = MF(ah, bv[ct], acc8[ct]);
                acc8[ct] = MF(al, bv[ct], acc8[ct]);
            }
        }
    }
    __syncthreads();
    if (half == 0) {
        const int m0 = ri0 + q * 4;
#pragma unroll
        for (int ct = 0; ct < 8; ++ct) {
            const int n = ct * 16 + l15;
            const int off = NSW(n, m0);
            s16x4 yh = *(s16x4*)(&Yhi[off]);
            s16x4 yl = *(s16x4*)(&Ylo[off]);
            s16x4 nh, nl;
#pragma unroll
            for (int r = 0; r < 4; ++r) {
                const float y = b2f((unsigned short)yh[r]) + b2f((unsigned short)yl[r]) + acc8[ct][r];
                unsigned short hh = f2b(y);
                nh[r] = (short)hh;
                nl[r] = (short)f2b(y - b2f(hh));
            }
            *(s16x4*)(&Yhi[off]) = nh;
            *(s16x4*)(&Ylo[off]) = nl;
        }
    }
    __syncthreads();

    // ======== it2..4: full update ========
#pragma unroll 1
    for (int it = 2; it <= 4; ++it) {
        // P1 (all 16 waves): D = 0.5I - 0.5 * Z@Y (Y ~ Yhi)
        f32x4 acc4[2][2];
#pragma unroll
        for (int rt = 0; rt < 2; ++rt)
#pragma unroll
            for (int ct = 0; ct < 2; ++ct) acc4[rt][ct] = (f32x4){0.f, 0.f, 0.f, 0.f};
#pragma unroll
        for (int k0 = 0; k0 < 128; k0 += 32) {
            const int ka = k0 + q * 8;
            s16x8 av[2], bv[2];
#pragma unroll
            for (int t = 0; t < 2; ++t) {
                av[t] = *(const s16x8*)(&Zm [NSW(p1i + t * 16 + l15, ka)]);
                bv[t] = *(const s16x8*)(&Yhi[NSW(p1j + t * 16 + l15, ka)]);
            }
#pragma unroll
            for (int rt = 0; rt < 2; ++rt)
#pragma unroll
                for (int ct = 0; ct < 2; ++ct)
                    acc4[rt][ct] = MF(av[rt], bv[ct], acc4[rt][ct]);
        }
#pragma unroll
        for (int rt = 0; rt < 2; ++rt)
#pragma unroll
            for (int ct = 0; ct < 2; ++ct) {
                const int m0 = p1i + rt * 16 + q * 4;
                const int n  = p1j + ct * 16 + l15;
                s16x4 dv;
#pragma unroll
                for (int r = 0; r < 4; ++r) {
                    const float dia = (m0 + r == n) ? 0.5f : 0.0f;
                    dv[r] = (short)f2b(dia - 0.5f * acc4[rt][ct][r]);
                }
                *(s16x4*)(&Dm[NSW(n, m0)]) = dv;
            }
        __syncthreads();

        // P2 (waves 0-7) || P3 (waves 8-15)
#pragma unroll
        for (int ct = 0; ct < 8; ++ct) acc8[ct] = (f32x4){0.f, 0.f, 0.f, 0.f};
        if (half == 0) {
#pragma unroll
            for (int k0 = 0; k0 < 128; k0 += 32) {
                const int ka = k0 + q * 8;
                s16x8 ah = *(const s16x8*)(&Yhi[NSW(ri0 + l15, ka)]);
                s16x8 al = *(const s16x8*)(&Ylo[NSW(ri0 + l15, ka)]);
                s16x8 bv[8];
#pragma unroll
                for (int ct = 0; ct < 8; ++ct)
                    bv[ct] = *(const s16x8*)(&Dm[NSW(ct * 16 + l15, ka)]);
#pragma unroll
                for (int ct = 0; ct < 8; ++ct) {
                    acc8[ct] = MF(ah, bv[ct], acc8[ct]);
                    acc8[ct] = MF(al, bv[ct], acc8[ct]);
                }
            }
        } else {
#pragma unroll
            for (int k0 = 0; k0 < 128; k0 += 32) {
                const int ka = k0 + q * 8;
                s16x8 av = *(const s16x8*)(&Dm[NSW(ri0 + l15, ka)]);
                s16x8 bv[8];
#pragma unroll
                for (int ct = 0; ct < 8; ++ct)
                    bv[ct] = *(const s16x8*)(&Zm[NSW(ct * 16 + l15, ka)]);
#pragma unroll
                for (int ct = 0; ct < 8; ++ct)
                    acc8[ct] = MF(av, bv[ct], acc8[ct]);
            }
        }
        __syncthreads();   // all plane reads complete before rewrites

        const int m0 = ri0 + q * 4;
        if (half == 0) {
#pragma unroll
            for (int ct = 0; ct < 8; ++ct) {
                const int n = ct * 16 + l15;
                const int off = NSW(n, m0);
                s16x4 yh = *(s16x4*)(&Yhi[off]);
                s16x4 yl = *(s16x4*)(&Ylo[off]);
                s16x4 nh, nl;
#pragma unroll
                for (int r = 0; r < 4; ++r) {
                    const float y = b2f((unsigned short)yh[r]) + b2f((unsigned short)yl[r]) + acc8[ct][r];
                    unsigned short hh = f2b(y);
                    nh[r] = (short)hh;
                    nl[r] = (short)f2b(y - b2f(hh));
                }
                *(s16x4*)(&Yhi[off]) = nh;
                *(s16x4*)(&Ylo[off]) = nl;
            }
        } else {
#pragma unroll
            for (int ct = 0; ct < 8; ++ct) {
                const int n = ct * 16 + l15;
                const int off = NSW(n, m0);
                s16x4 zv = *(s16x4*)(&Zm[off]);
                s16x4 zn;
#pragma unroll
                for (int r = 0; r < 4; ++r)
                    zn[r] = (short)f2b(b2f((unsigned short)zv[r]) + acc8[ct][r]);
                *(s16x4*)(&Zm[off]) = zn;
            }
        }
        __syncthreads();
    }

    // ======== it5: P1, then P2 -> output ========
    {
        f32x4 acc4[2][2];
#pragma unroll
        for (int rt = 0; rt < 2; ++rt)
#pragma unroll
            for (int ct = 0; ct < 2; ++ct) acc4[rt][ct] = (f32x4){0.f, 0.f, 0.f, 0.f};
#pragma unroll
        for (int k0 = 0; k0 < 128; k0 += 32) {
            const int ka = k0 + q * 8;
            s16x8 av[2], bv[2];
#pragma unroll
            for (int t = 0; t < 2; ++t) {
                av[t] = *(const s16x8*)(&Zm [NSW(p1i + t * 16 + l15, ka)]);
                bv[t] = *(const s16x8*)(&Yhi[NSW(p1j + t * 16 + l15, ka)]);
            }
#pragma unroll
            for (int rt = 0; rt < 2; ++rt)
#pragma unroll
                for (int ct = 0; ct < 2; ++ct)
                    acc4[rt][ct] = MF(av[rt], bv[ct], acc4[rt][ct]);
        }
#pragma unroll
        for (int rt = 0; rt < 2; ++rt)
#pragma unroll
            for (int ct = 0; ct < 2; ++ct) {
                const int m0 = p1i + rt * 16 + q * 4;
                const int n  = p1j + ct * 16 + l15;
                s16x4 dv;
#pragma unroll
                for (int r = 0; r < 4; ++r) {
                    const float dia = (m0 + r == n) ? 0.5f : 0.0f;
                    dv[r] = (short)f2b(dia - 0.5f * acc4[rt][ct][r]);
                }
                *(s16x4*)(&Dm[NSW(n, m0)]) = dv;
            }
        __syncthreads();

        if (half == 0) {
#pragma unroll
            for (int ct = 0; ct < 8; ++ct) acc8[ct] = (f32x4){0.f, 0.f, 0.f, 0.f};
#pragma unroll
            for (int k0 = 0; k0 < 128; k0 += 32) {
                const int ka = k0 + q * 8;
                s16x8 ah = *(const s16x8*)(&Yhi[NSW(ri0 + l15, ka)]);
                s16x8 al = *(const s16x8*)(&Ylo[NSW(ri0 + l15, ka)]);
                s16x8 bv[8];
#pragma unroll
                for (int ct = 0; ct < 8; ++ct)
                    bv[ct] = *(const s16x8*)(&Dm[NSW(ct * 16 + l15, ka)]);
#pragma unroll
                for (int ct = 0; ct < 8; ++ct) {
                    acc8[ct] = MF(ah, bv[ct], acc8[ct]);
                    acc8[ct] = MF(al, bv[ct], acc8[ct]);
                }
            }
            // out = triu(Y5 + Y5@D5) * sqrt(tr); Yhi/Ylo stable (no writers)
            float* __restrict__ ob = out + (size_t)b * OUTLEN;
            const int m0 = ri0 + q * 4;
#pragma unroll
            for (int ct = 0; ct < 8; ++ct) {
                const int n = ct * 16 + l15;
                const int off = NSW(n, m0);
                s16x4 yh = *(s16x4*)(&Yhi[off]);
                s16x4 yl = *(s16x4*)(&Ylo[off]);
#pragma unroll
                for (int r = 0; r < 4; ++r) {
                    const int m = m0 + r;
                    if (m <= n) {
                        const float y = b2f((unsigned short)yh[r]) + b2f((unsigned short)yl[r]) + acc8[ct][r];
                        ob[m * CC - ((m * (m - 1)) >> 1) + (n - m)] = y * sscale;
                    }
                }
            }
        }
    }
}

extern "C" void kernel_launch(void* const* d_in, const int* in_sizes, int n_in,
                              void* d_out, int out_size, void* d_ws, size_t ws_size,
                              hipStream_t stream)
{
    (void)in_sizes; (void)n_in; (void)out_size; (void)ws_size;
    const float* x = (const float*)d_in[0];
    float* out = (float*)d_out;
    float* ws  = (float*)d_ws;

    float* trpart = ws;                                   // 256 floats
    float* rspart = ws + 256;                             // KS*BB*CC floats
    float* Gpart  = rspart + (size_t)KS * BB * CC;        // KS*BB*MATS floats
    short* Shi    = (short*)(Gpart + (size_t)KS * BB * MATS);  // BB*MATS shorts
    short* Slo    = Shi + (size_t)BB * MATS;                   // BB*MATS shorts

    gram_kernel<<<dim3(BB, KS), 256, 0, stream>>>(x, Gpart, rspart);
    reduce_kernel<<<dim3(BB, 4), 256, 0, stream>>>(Gpart, rspart, Shi, Slo, trpart);
    ns_kernel<<<dim3(BB), 1024, 0, stream>>>(Shi, Slo, trpart, out);
}